// Round 6
// baseline (122.769 us; speedup 1.0000x reference)
//
#include <hip/hip_runtime.h>

#define BB 8
#define CC 64
#define HH 256
#define WW 256
#define DSF 8
#define HP 32
#define WP 32
#define NN 1024  // HP*WP

typedef _Float16 f16x4 __attribute__((ext_vector_type(4)));
typedef float f32x4 __attribute__((ext_vector_type(4)));

// ---------------------------------------------------------------------------
// K1: 8x8 avg-pool. One THREAD = one pooled output (8x8 box): 16 independent
// global_load_dwordx4 off one base address (immediate offsets 0..7184B), pure
// per-thread reduce, no shfl/LDS/barriers. 4096 blocks: first 2048 -> x
// (L3-resident from previous replay's k_out), last 2048 -> diff.
// Block = quarter plane = 256 pooled outputs; stores fully coalesced.
// ---------------------------------------------------------------------------
__global__ __launch_bounds__(256) void k_pool(const float* __restrict__ x,
                                              const float* __restrict__ diff,
                                              float* __restrict__ dpool,
                                              float* __restrict__ pxpool) {
    int bid = blockIdx.x;
    int which = bid < 2048 ? 1 : 0;   // 1 = x, 0 = diff
    int r = bid & 2047;
    int plane = r >> 2;               // b*CC + c
    int g = r & 3;                    // quarter within plane
    int t = threadIdx.x;
    int p = g * 256 + t;              // pooled index in plane [0,1024)
    int prow = p >> 5, pcol = p & 31;
    const float* rb = (which ? x : diff)
                      + (size_t)plane * (HH * WW) + (size_t)(prow * 8) * WW + pcol * 8;
    f32x4 v[16];
#pragma unroll
    for (int rr = 0; rr < 8; ++rr) {
#pragma unroll
        for (int h = 0; h < 2; ++h)
            v[rr * 2 + h] = *(const f32x4*)(rb + rr * WW + 4 * h);
    }
    float s = 0.f;
#pragma unroll
    for (int i = 0; i < 16; ++i)
        s += (v[i][0] + v[i][1]) + (v[i][2] + v[i][3]);
    float* dst = (which ? pxpool : dpool) + (size_t)plane * NN + p;
    *dst = s * (1.f / 64.f);
}

// ---------------------------------------------------------------------------
// K2: projections -> f16 in MFMA-friendly layouts (unchanged).
// ---------------------------------------------------------------------------
__global__ __launch_bounds__(256) void k_proj(const float* __restrict__ dpool,
                                              const float* __restrict__ pxpool,
                                              const float* __restrict__ Wq, const float* __restrict__ bq,
                                              const float* __restrict__ Wk, const float* __restrict__ bk,
                                              const float* __restrict__ Wv, const float* __restrict__ bv,
                                              _Float16* __restrict__ qt, _Float16* __restrict__ kt,
                                              _Float16* __restrict__ vct) {
    __shared__ float Ws[64 * 65];
    __shared__ float dsh[64 * 68];
    int bid = blockIdx.x;
    int proj = bid >> 7;
    int rem = bid & 127;
    int b = rem >> 4;
    int n0 = (rem & 15) * 64;
    const float* Wm; const float* bias; const float* src;
    if (proj == 0)      { Wm = Wq; bias = bq; src = dpool; }
    else if (proj == 1) { Wm = Wk; bias = bk; src = dpool; }
    else                { Wm = Wv; bias = bv; src = pxpool; }
    int t = threadIdx.x;
#pragma unroll
    for (int i = 0; i < 16; ++i) {
        int e = t + i * 256;
        int o = e >> 6, c = e & 63;
        Ws[o * 65 + c] = Wm[e];
        dsh[o * 68 + c] = src[(size_t)(b * CC + o) * NN + n0 + c];
    }
    __syncthreads();
    int o = t & 63;
    int ng = t >> 6;
    float bb = bias[o];
    float4 acc[4];
#pragma unroll
    for (int j = 0; j < 4; ++j) acc[j] = make_float4(bb, bb, bb, bb);
#pragma unroll 8
    for (int c = 0; c < 64; ++c) {
        float wv = Ws[o * 65 + c];
        const float4* dr = (const float4*)(dsh + c * 68 + ng * 16);
#pragma unroll
        for (int j = 0; j < 4; ++j) {
            float4 d4 = dr[j];
            acc[j].x += wv * d4.x; acc[j].y += wv * d4.y;
            acc[j].z += wv * d4.z; acc[j].w += wv * d4.w;
        }
    }
    if (proj == 2) {
        _Float16* outp = vct + (size_t)(b * CC + o) * NN + n0 + ng * 16;
#pragma unroll
        for (int j = 0; j < 4; ++j) {
            f16x4 h;
            h[0] = (_Float16)acc[j].x; h[1] = (_Float16)acc[j].y;
            h[2] = (_Float16)acc[j].z; h[3] = (_Float16)acc[j].w;
            *(f16x4*)(outp + 4 * j) = h;
        }
    } else {
        __syncthreads();
#pragma unroll
        for (int j = 0; j < 4; ++j)
            *(float4*)(&dsh[o * 68 + ng * 16 + 4 * j]) = acc[j];
        __syncthreads();
        int nl = t & 63, og = t >> 6;
        float scale = (proj == 0) ? 0.125f : 1.0f;
        _Float16* outp = (proj == 0 ? qt : kt) + (size_t)(b * NN + n0 + nl) * CC + og * 16;
#pragma unroll
        for (int jj = 0; jj < 4; ++jj) {
            f16x4 h;
#pragma unroll
            for (int q4 = 0; q4 < 4; ++q4)
                h[q4] = (_Float16)(dsh[(og * 16 + 4 * jj + q4) * 68 + nl] * scale);
            *(f16x4*)(outp + 4 * jj) = h;
        }
    }
}

// ---------------------------------------------------------------------------
// K3: MFMA attention (unchanged). One block = (b, 16-query tile).
// ---------------------------------------------------------------------------
__global__ __launch_bounds__(256) void k_attn(const _Float16* __restrict__ qt,
                                              const _Float16* __restrict__ kt,
                                              const _Float16* __restrict__ vct,
                                              float* __restrict__ op) {
#define PS 1036
    __shared__ __align__(16) _Float16 P[16 * PS];
    __shared__ float part[4 * 16 * 65];
    __shared__ float wmax[4][16];
    __shared__ float wsum[4][16];
    int bid = blockIdx.x;
    int b = bid >> 6;
    int n0 = (bid & 63) * 16;
    int t = threadIdx.x;
    int w = t >> 6, l = t & 63;
    int lo = l & 15, g = l >> 4;

    const _Float16* qb = qt + (size_t)(b * NN + n0) * CC;
    const _Float16* kb = kt + (size_t)b * NN * CC;
    const _Float16* vb = vct + (size_t)b * CC * NN;

    f16x4 aq[4];
#pragma unroll
    for (int kc = 0; kc < 4; ++kc)
        aq[kc] = *(const f16x4*)(qb + lo * CC + 16 * kc + 4 * g);

    int mbase = w * 256;
    f32x4 e[16];
#pragma unroll
    for (int tm = 0; tm < 16; ++tm) e[tm] = (f32x4){0.f, 0.f, 0.f, 0.f};
#pragma unroll
    for (int tm = 0; tm < 16; ++tm) {
        int m = mbase + 16 * tm + lo;
        const _Float16* kr = kb + (size_t)m * CC + 4 * g;
#pragma unroll
        for (int kc = 0; kc < 4; ++kc) {
            f16x4 bk = *(const f16x4*)(kr + 16 * kc);
            e[tm] = __builtin_amdgcn_mfma_f32_16x16x16f16(aq[kc], bk, e[tm], 0, 0, 0);
        }
    }
    float mx[4], sm[4];
#pragma unroll
    for (int r = 0; r < 4; ++r) {
        float m_ = -1e30f;
#pragma unroll
        for (int tm = 0; tm < 16; ++tm) m_ = fmaxf(m_, e[tm][r]);
#pragma unroll
        for (int off = 8; off; off >>= 1) m_ = fmaxf(m_, __shfl_xor(m_, off));
        mx[r] = m_;
    }
    if (lo == 0) {
#pragma unroll
        for (int r = 0; r < 4; ++r) wmax[w][4 * g + r] = mx[r];
    }
    __syncthreads();
#pragma unroll
    for (int r = 0; r < 4; ++r) {
        int n = 4 * g + r;
        mx[r] = fmaxf(fmaxf(wmax[0][n], wmax[1][n]), fmaxf(wmax[2][n], wmax[3][n]));
        sm[r] = 0.f;
    }
#pragma unroll
    for (int tm = 0; tm < 16; ++tm) {
        int mcol = mbase + 16 * tm + lo;
#pragma unroll
        for (int r = 0; r < 4; ++r) {
            float p = __expf(e[tm][r] - mx[r]);
            sm[r] += p;
            P[(4 * g + r) * PS + mcol] = (_Float16)p;
        }
    }
#pragma unroll
    for (int r = 0; r < 4; ++r) {
#pragma unroll
        for (int off = 8; off; off >>= 1) sm[r] += __shfl_xor(sm[r], off);
    }
    if (lo == 0) {
#pragma unroll
        for (int r = 0; r < 4; ++r) wsum[w][4 * g + r] = sm[r];
    }
    f32x4 o4[4];
#pragma unroll
    for (int tc = 0; tc < 4; ++tc) o4[tc] = (f32x4){0.f, 0.f, 0.f, 0.f};
#pragma unroll
    for (int mk = 0; mk < 16; ++mk) {
        f16x4 pa = *(const f16x4*)(&P[lo * PS + mbase + 16 * mk + 4 * g]);
        const _Float16* vr = vb + mbase + 16 * mk + 4 * g;
#pragma unroll
        for (int tc = 0; tc < 4; ++tc) {
            f16x4 bv_ = *(const f16x4*)(vr + (size_t)(lo + 16 * tc) * NN);
            o4[tc] = __builtin_amdgcn_mfma_f32_16x16x16f16(pa, bv_, o4[tc], 0, 0, 0);
        }
    }
#pragma unroll
    for (int tc = 0; tc < 4; ++tc)
#pragma unroll
        for (int r = 0; r < 4; ++r)
            part[(w * 16 + 4 * g + r) * 65 + lo + 16 * tc] = o4[tc][r];
    __syncthreads();
#pragma unroll
    for (int i = 0; i < 4; ++i) {
        int e2 = t + i * 256;
        int c = e2 >> 4, n = e2 & 15;
        float s = part[(0 * 16 + n) * 65 + c] + part[(1 * 16 + n) * 65 + c] +
                  part[(2 * 16 + n) * 65 + c] + part[(3 * 16 + n) * 65 + c];
        float denom = wsum[0][n] + wsum[1][n] + wsum[2][n] + wsum[3][n];
        op[(size_t)(b * CC + c) * NN + n0 + n] = s / denom;
    }
#undef PS
}

// ---------------------------------------------------------------------------
// K4: out = nearest-upsample(op, 8) + x. Coalesced float4, nt store (out is
// never re-read; keeps L3 space for x).
// ---------------------------------------------------------------------------
__global__ __launch_bounds__(256) void k_out(const float* __restrict__ x,
                                             const float* __restrict__ op,
                                             float* __restrict__ out) {
    int t = threadIdx.x;
#pragma unroll
    for (int i = 0; i < 2; ++i) {
        size_t idx4 = (size_t)blockIdx.x * 512 + i * 256 + t;
        size_t flat = idx4 * 4;
        int w = (int)(flat & 255);
        int h = (int)((flat >> 8) & 255);
        int bc = (int)(flat >> 16);
        float ov = op[(size_t)bc * NN + (h >> 3) * WP + (w >> 3)];
        float4 xv = *(const float4*)(x + flat);
        f32x4 r = {xv.x + ov, xv.y + ov, xv.z + ov, xv.w + ov};
        __builtin_nontemporal_store(r, (f32x4*)(out + flat));
    }
}

extern "C" void kernel_launch(void* const* d_in, const int* in_sizes, int n_in,
                              void* d_out, int out_size, void* d_ws, size_t ws_size,
                              hipStream_t stream) {
    const float* x    = (const float*)d_in[0];
    const float* diff = (const float*)d_in[1];
    const float* Wq   = (const float*)d_in[2];
    const float* bq   = (const float*)d_in[3];
    const float* Wk   = (const float*)d_in[4];
    const float* bk   = (const float*)d_in[5];
    const float* Wv   = (const float*)d_in[6];
    const float* bv   = (const float*)d_in[7];
    float* ws = (float*)d_ws;
    float* dpool  = ws;                    // 524288 floats
    float* pxpool = ws + 524288;
    float* op     = ws + 1048576;
    _Float16* qt  = (_Float16*)(ws + 1572864);
    _Float16* kt  = (_Float16*)(ws + 1835008);
    _Float16* vct = (_Float16*)(ws + 2097152);
    float* out = (float*)d_out;

    hipLaunchKernelGGL(k_pool, dim3(4096), dim3(256), 0, stream, x, diff, dpool, pxpool);
    hipLaunchKernelGGL(k_proj, dim3(384), dim3(256), 0, stream, dpool, pxpool,
                       Wq, bq, Wk, bk, Wv, bv, qt, kt, vct);
    hipLaunchKernelGGL(k_attn, dim3(512), dim3(256), 0, stream, qt, kt, vct, op);
    hipLaunchKernelGGL(k_out, dim3(16384), dim3(256), 0, stream, x, op, out);
}

// Round 7
// 121.259 us; speedup vs baseline: 1.0124x; 1.0124x over previous
//
#include <hip/hip_runtime.h>

#define BB 8
#define CC 64
#define HH 256
#define WW 256
#define DSF 8
#define HP 32
#define WP 32
#define NN 1024  // HP*WP

typedef _Float16 f16x4 __attribute__((ext_vector_type(4)));
typedef float f32x4 __attribute__((ext_vector_type(4)));

__device__ __forceinline__ void gl_lds16(const float* g, float* l) {
    __builtin_amdgcn_global_load_lds(
        (const __attribute__((address_space(1))) unsigned int*)g,
        (__attribute__((address_space(3))) unsigned int*)l, 16, 0, 0);
}

// ---------------------------------------------------------------------------
// K1: 8x8 avg-pool via global_load_lds (direct-to-LDS, no VGPR return slot):
// each wave owns a private 2x8KB double buffer and streams 8 pooled rows
// (tile = 8 input rows = 8 global_load_lds_dwordx4, 1KB each). Counted
// vmcnt (8/9/1, never 0), NO __syncthreads -> up to 16KB in flight per wave.
// 1024 blocks (x/diff interleaved), block = one (b,c) plane, wave w handles
// pooled rows 4*it + w.
// ---------------------------------------------------------------------------
__global__ __launch_bounds__(256) void k_pool(const float* __restrict__ x,
                                              const float* __restrict__ diff,
                                              float* __restrict__ dpool,
                                              float* __restrict__ pxpool) {
    __shared__ float buf[4][2][2048];   // [wave][dbuf][8 rows x 256]
    int bid = blockIdx.x;
    int which = bid & 1;                // interleave: 1 = x, 0 = diff
    int plane = bid >> 1;               // b*CC + c
    const float* base = (which ? x : diff) + (size_t)plane * (HH * WW);
    float* dst = (which ? pxpool : dpool) + (size_t)plane * NN;
    int t = threadIdx.x;
    int w = t >> 6, lane = t & 63;

    // stage tile for pooled row pr into slot
    auto stage = [&](int pr, int slot) {
        const float* grow = base + (size_t)(pr * 8) * WW + lane * 4;
#pragma unroll
        for (int r = 0; r < 8; ++r)
            gl_lds16(grow + r * WW, &buf[w][slot][r * 256]);
    };

    stage(w, 0);                        // prologue: tile 0 of this wave
#pragma unroll
    for (int it = 0; it < 8; ++it) {
        int pr = 4 * it + w;
        if (it < 7) stage(4 * (it + 1) + w, (it + 1) & 1);
        if (it == 0)      asm volatile("s_waitcnt vmcnt(8)" ::: "memory");
        else if (it < 7)  asm volatile("s_waitcnt vmcnt(9)" ::: "memory");
        else              asm volatile("s_waitcnt vmcnt(1)" ::: "memory");
        __builtin_amdgcn_sched_barrier(0);
        int h = lane >> 5, pcol = lane & 31;
        const f32x4* b4 = (const f32x4*)&buf[w][it & 1][0];
        float s = 0.f;
#pragma unroll
        for (int rr = 0; rr < 4; ++rr) {
            f32x4 a = b4[(h * 4 + rr) * 64 + pcol * 2];
            f32x4 c = b4[(h * 4 + rr) * 64 + pcol * 2 + 1];
            s += (a[0] + a[1]) + (a[2] + a[3]) + (c[0] + c[1]) + (c[2] + c[3]);
        }
        s += __shfl_xor(s, 32);
        if (h == 0)
            dst[pr * 32 + pcol] = s * (1.f / 64.f);
    }
}

// ---------------------------------------------------------------------------
// K2: projections -> f16 in MFMA-friendly layouts (unchanged).
// ---------------------------------------------------------------------------
__global__ __launch_bounds__(256) void k_proj(const float* __restrict__ dpool,
                                              const float* __restrict__ pxpool,
                                              const float* __restrict__ Wq, const float* __restrict__ bq,
                                              const float* __restrict__ Wk, const float* __restrict__ bk,
                                              const float* __restrict__ Wv, const float* __restrict__ bv,
                                              _Float16* __restrict__ qt, _Float16* __restrict__ kt,
                                              _Float16* __restrict__ vct) {
    __shared__ float Ws[64 * 65];
    __shared__ float dsh[64 * 68];
    int bid = blockIdx.x;
    int proj = bid >> 7;
    int rem = bid & 127;
    int b = rem >> 4;
    int n0 = (rem & 15) * 64;
    const float* Wm; const float* bias; const float* src;
    if (proj == 0)      { Wm = Wq; bias = bq; src = dpool; }
    else if (proj == 1) { Wm = Wk; bias = bk; src = dpool; }
    else                { Wm = Wv; bias = bv; src = pxpool; }
    int t = threadIdx.x;
#pragma unroll
    for (int i = 0; i < 16; ++i) {
        int e = t + i * 256;
        int o = e >> 6, c = e & 63;
        Ws[o * 65 + c] = Wm[e];
        dsh[o * 68 + c] = src[(size_t)(b * CC + o) * NN + n0 + c];
    }
    __syncthreads();
    int o = t & 63;
    int ng = t >> 6;
    float bb = bias[o];
    float4 acc[4];
#pragma unroll
    for (int j = 0; j < 4; ++j) acc[j] = make_float4(bb, bb, bb, bb);
#pragma unroll 8
    for (int c = 0; c < 64; ++c) {
        float wv = Ws[o * 65 + c];
        const float4* dr = (const float4*)(dsh + c * 68 + ng * 16);
#pragma unroll
        for (int j = 0; j < 4; ++j) {
            float4 d4 = dr[j];
            acc[j].x += wv * d4.x; acc[j].y += wv * d4.y;
            acc[j].z += wv * d4.z; acc[j].w += wv * d4.w;
        }
    }
    if (proj == 2) {
        _Float16* outp = vct + (size_t)(b * CC + o) * NN + n0 + ng * 16;
#pragma unroll
        for (int j = 0; j < 4; ++j) {
            f16x4 h;
            h[0] = (_Float16)acc[j].x; h[1] = (_Float16)acc[j].y;
            h[2] = (_Float16)acc[j].z; h[3] = (_Float16)acc[j].w;
            *(f16x4*)(outp + 4 * j) = h;
        }
    } else {
        __syncthreads();
#pragma unroll
        for (int j = 0; j < 4; ++j)
            *(float4*)(&dsh[o * 68 + ng * 16 + 4 * j]) = acc[j];
        __syncthreads();
        int nl = t & 63, og = t >> 6;
        float scale = (proj == 0) ? 0.125f : 1.0f;
        _Float16* outp = (proj == 0 ? qt : kt) + (size_t)(b * NN + n0 + nl) * CC + og * 16;
#pragma unroll
        for (int jj = 0; jj < 4; ++jj) {
            f16x4 h;
#pragma unroll
            for (int q4 = 0; q4 < 4; ++q4)
                h[q4] = (_Float16)(dsh[(og * 16 + 4 * jj + q4) * 68 + nl] * scale);
            *(f16x4*)(outp + 4 * jj) = h;
        }
    }
}

// ---------------------------------------------------------------------------
// K3: MFMA attention (unchanged). One block = (b, 16-query tile).
// ---------------------------------------------------------------------------
__global__ __launch_bounds__(256) void k_attn(const _Float16* __restrict__ qt,
                                              const _Float16* __restrict__ kt,
                                              const _Float16* __restrict__ vct,
                                              float* __restrict__ op) {
#define PS 1036
    __shared__ __align__(16) _Float16 P[16 * PS];
    __shared__ float part[4 * 16 * 65];
    __shared__ float wmax[4][16];
    __shared__ float wsum[4][16];
    int bid = blockIdx.x;
    int b = bid >> 6;
    int n0 = (bid & 63) * 16;
    int t = threadIdx.x;
    int w = t >> 6, l = t & 63;
    int lo = l & 15, g = l >> 4;

    const _Float16* qb = qt + (size_t)(b * NN + n0) * CC;
    const _Float16* kb = kt + (size_t)b * NN * CC;
    const _Float16* vb = vct + (size_t)b * CC * NN;

    f16x4 aq[4];
#pragma unroll
    for (int kc = 0; kc < 4; ++kc)
        aq[kc] = *(const f16x4*)(qb + lo * CC + 16 * kc + 4 * g);

    int mbase = w * 256;
    f32x4 e[16];
#pragma unroll
    for (int tm = 0; tm < 16; ++tm) e[tm] = (f32x4){0.f, 0.f, 0.f, 0.f};
#pragma unroll
    for (int tm = 0; tm < 16; ++tm) {
        int m = mbase + 16 * tm + lo;
        const _Float16* kr = kb + (size_t)m * CC + 4 * g;
#pragma unroll
        for (int kc = 0; kc < 4; ++kc) {
            f16x4 bk = *(const f16x4*)(kr + 16 * kc);
            e[tm] = __builtin_amdgcn_mfma_f32_16x16x16f16(aq[kc], bk, e[tm], 0, 0, 0);
        }
    }
    float mx[4], sm[4];
#pragma unroll
    for (int r = 0; r < 4; ++r) {
        float m_ = -1e30f;
#pragma unroll
        for (int tm = 0; tm < 16; ++tm) m_ = fmaxf(m_, e[tm][r]);
#pragma unroll
        for (int off = 8; off; off >>= 1) m_ = fmaxf(m_, __shfl_xor(m_, off));
        mx[r] = m_;
    }
    if (lo == 0) {
#pragma unroll
        for (int r = 0; r < 4; ++r) wmax[w][4 * g + r] = mx[r];
    }
    __syncthreads();
#pragma unroll
    for (int r = 0; r < 4; ++r) {
        int n = 4 * g + r;
        mx[r] = fmaxf(fmaxf(wmax[0][n], wmax[1][n]), fmaxf(wmax[2][n], wmax[3][n]));
        sm[r] = 0.f;
    }
#pragma unroll
    for (int tm = 0; tm < 16; ++tm) {
        int mcol = mbase + 16 * tm + lo;
#pragma unroll
        for (int r = 0; r < 4; ++r) {
            float p = __expf(e[tm][r] - mx[r]);
            sm[r] += p;
            P[(4 * g + r) * PS + mcol] = (_Float16)p;
        }
    }
#pragma unroll
    for (int r = 0; r < 4; ++r) {
#pragma unroll
        for (int off = 8; off; off >>= 1) sm[r] += __shfl_xor(sm[r], off);
    }
    if (lo == 0) {
#pragma unroll
        for (int r = 0; r < 4; ++r) wsum[w][4 * g + r] = sm[r];
    }
    f32x4 o4[4];
#pragma unroll
    for (int tc = 0; tc < 4; ++tc) o4[tc] = (f32x4){0.f, 0.f, 0.f, 0.f};
#pragma unroll
    for (int mk = 0; mk < 16; ++mk) {
        f16x4 pa = *(const f16x4*)(&P[lo * PS + mbase + 16 * mk + 4 * g]);
        const _Float16* vr = vb + mbase + 16 * mk + 4 * g;
#pragma unroll
        for (int tc = 0; tc < 4; ++tc) {
            f16x4 bv_ = *(const f16x4*)(vr + (size_t)(lo + 16 * tc) * NN);
            o4[tc] = __builtin_amdgcn_mfma_f32_16x16x16f16(pa, bv_, o4[tc], 0, 0, 0);
        }
    }
#pragma unroll
    for (int tc = 0; tc < 4; ++tc)
#pragma unroll
        for (int r = 0; r < 4; ++r)
            part[(w * 16 + 4 * g + r) * 65 + lo + 16 * tc] = o4[tc][r];
    __syncthreads();
#pragma unroll
    for (int i = 0; i < 4; ++i) {
        int e2 = t + i * 256;
        int c = e2 >> 4, n = e2 & 15;
        float s = part[(0 * 16 + n) * 65 + c] + part[(1 * 16 + n) * 65 + c] +
                  part[(2 * 16 + n) * 65 + c] + part[(3 * 16 + n) * 65 + c];
        float denom = wsum[0][n] + wsum[1][n] + wsum[2][n] + wsum[3][n];
        op[(size_t)(b * CC + c) * NN + n0 + n] = s / denom;
    }
#undef PS
}

// ---------------------------------------------------------------------------
// K4: out = nearest-upsample(op, 8) + x. Coalesced float4, nt store.
// ---------------------------------------------------------------------------
__global__ __launch_bounds__(256) void k_out(const float* __restrict__ x,
                                             const float* __restrict__ op,
                                             float* __restrict__ out) {
    int t = threadIdx.x;
#pragma unroll
    for (int i = 0; i < 2; ++i) {
        size_t idx4 = (size_t)blockIdx.x * 512 + i * 256 + t;
        size_t flat = idx4 * 4;
        int w = (int)(flat & 255);
        int h = (int)((flat >> 8) & 255);
        int bc = (int)(flat >> 16);
        float ov = op[(size_t)bc * NN + (h >> 3) * WP + (w >> 3)];
        float4 xv = *(const float4*)(x + flat);
        f32x4 r = {xv.x + ov, xv.y + ov, xv.z + ov, xv.w + ov};
        __builtin_nontemporal_store(r, (f32x4*)(out + flat));
    }
}

extern "C" void kernel_launch(void* const* d_in, const int* in_sizes, int n_in,
                              void* d_out, int out_size, void* d_ws, size_t ws_size,
                              hipStream_t stream) {
    const float* x    = (const float*)d_in[0];
    const float* diff = (const float*)d_in[1];
    const float* Wq   = (const float*)d_in[2];
    const float* bq   = (const float*)d_in[3];
    const float* Wk   = (const float*)d_in[4];
    const float* bk   = (const float*)d_in[5];
    const float* Wv   = (const float*)d_in[6];
    const float* bv   = (const float*)d_in[7];
    float* ws = (float*)d_ws;
    float* dpool  = ws;                    // 524288 floats
    float* pxpool = ws + 524288;
    float* op     = ws + 1048576;
    _Float16* qt  = (_Float16*)(ws + 1572864);
    _Float16* kt  = (_Float16*)(ws + 1835008);
    _Float16* vct = (_Float16*)(ws + 2097152);
    float* out = (float*)d_out;

    hipLaunchKernelGGL(k_pool, dim3(1024), dim3(256), 0, stream, x, diff, dpool, pxpool);
    hipLaunchKernelGGL(k_proj, dim3(384), dim3(256), 0, stream, dpool, pxpool,
                       Wq, bq, Wk, bk, Wv, bv, qt, kt, vct);
    hipLaunchKernelGGL(k_attn, dim3(512), dim3(256), 0, stream, qt, kt, vct, op);
    hipLaunchKernelGGL(k_out, dim3(16384), dim3(256), 0, stream, x, op, out);
}